// Round 6
// baseline (330.761 us; speedup 1.0000x reference)
//
#include <hip/hip_runtime.h>
#include <math.h>

typedef __bf16 bf16_t;
typedef bf16_t bf16x8 __attribute__((ext_vector_type(8)));
typedef bf16_t bf16x4 __attribute__((ext_vector_type(4)));
typedef float floatx4 __attribute__((ext_vector_type(4)));
typedef short short4v __attribute__((ext_vector_type(4)));

#define MFMA16(a, b, c) __builtin_amdgcn_mfma_f32_16x16x32_bf16((a), (b), (c), 0, 0, 0)

#if __has_builtin(__builtin_amdgcn_exp2f)
#define PEXP(x) __builtin_amdgcn_exp2f(x)
#define SCORE_SCALE (0.125f * 1.4426950408889634f)   // fold log2e into Q scale
#else
#define PEXP(x) __expf(x)
#define SCORE_SCALE 0.125f
#endif

#if __has_builtin(__builtin_amdgcn_mfma_f32_16x16x16bf16_1k)
#define HAVE_MFMA_K16 1
__device__ __forceinline__ floatx4 mfma_k16(bf16x4 a, bf16x4 b, floatx4 c)
{
    union { bf16x4 v; short4v s; } ua, ub;
    ua.v = a; ub.v = b;
    return __builtin_amdgcn_mfma_f32_16x16x16bf16_1k(ua.s, ub.s, c, 0, 0, 0);
}
#endif

union PU { unsigned u[2]; bf16x4 v; };
union BU { unsigned u[4]; bf16x8 v; };

// global -> LDS direct copy, 16 B per lane (wave-uniform LDS base + lane*16).
__device__ __forceinline__ void gld16(const void* g, void* lds)
{
    __builtin_amdgcn_global_load_lds(
        reinterpret_cast<const __attribute__((address_space(1))) void*>(
            reinterpret_cast<uintptr_t>(g)),
        reinterpret_cast<__attribute__((address_space(3))) void*>(
            (unsigned int)reinterpret_cast<uintptr_t>(lds)),
        16, 0, 0);
}

// ---------------------------------------------------------------------------
// m97-style GEMM body: C[M,N] = A[M,K] @ Bt[N,K]^T, bf16, fp32 accum.
// 128x128 tile, BK=64, 4 waves (2x2), each wave 64x64. XOR-swizzled LDS.
// ---------------------------------------------------------------------------
template <typename TC>
__device__ __forceinline__ void gemm_bt_body(
    const bf16_t* __restrict__ A, const bf16_t* __restrict__ Bt,
    TC* __restrict__ C, int row0, int col0, int N, int K,
    bf16_t* As, bf16_t* Bs)
{
    const int tid  = threadIdx.x;
    const int wave = tid >> 6, lane = tid & 63;
    const int quad = lane >> 4, l16 = lane & 15;
    const int wm = (wave >> 1) * 64, wn = (wave & 1) * 64;

    floatx4 acc[4][4] = {};

    for (int k0 = 0; k0 < K; k0 += 64) {
        __syncthreads();
        #pragma unroll
        for (int i = 0; i < 4; ++i) {
            int c = i * 256 + tid;
            int r = c >> 3, s = c & 7;
            int ks = k0 + ((s ^ (r & 7)) << 3);
            gld16(A  + (size_t)(row0 + r) * K + ks, &As[(i * 256 + wave * 64) * 8]);
            gld16(Bt + (size_t)(col0 + r) * K + ks, &Bs[(i * 256 + wave * 64) * 8]);
        }
        __syncthreads();
        #pragma unroll
        for (int kh = 0; kh < 2; ++kh) {
            bf16x8 af[4], bfr[4];
            #pragma unroll
            for (int t = 0; t < 4; ++t) {
                int ar = wm + t * 16 + l16;
                af[t]  = *(const bf16x8*)&As[ar * 64 + (((kh * 4 + quad) ^ (ar & 7)) << 3)];
                int br = wn + t * 16 + l16;
                bfr[t] = *(const bf16x8*)&Bs[br * 64 + (((kh * 4 + quad) ^ (br & 7)) << 3)];
            }
            #pragma unroll
            for (int mt = 0; mt < 4; ++mt)
                #pragma unroll
                for (int nt = 0; nt < 4; ++nt)
                    acc[mt][nt] = MFMA16(af[mt], bfr[nt], acc[mt][nt]);
        }
    }
    #pragma unroll
    for (int mt = 0; mt < 4; ++mt)
        #pragma unroll
        for (int nt = 0; nt < 4; ++nt)
            #pragma unroll
            for (int r = 0; r < 4; ++r)
                C[(size_t)(row0 + wm + mt * 16 + quad * 4 + r) * N
                  + col0 + wn + nt * 16 + l16] = (TC)acc[mt][nt][r];
}

template <typename TC>
__global__ __launch_bounds__(256) void gemm_bt(
    const bf16_t* __restrict__ A, const bf16_t* __restrict__ Bt,
    TC* __restrict__ C, int N, int K)
{
    __shared__ bf16_t As[128 * 64];
    __shared__ bf16_t Bs[128 * 64];
    gemm_bt_body<TC>(A, Bt, C, blockIdx.y * 128, blockIdx.x * 128, N, K, As, Bs);
}

// Fused Q+K+V projection. grid.x = 24: 0..15 -> Q, 16..19 -> K, 20..23 -> V.
__global__ __launch_bounds__(256) void gemm_qkv(
    const bf16_t* __restrict__ A, const bf16_t* __restrict__ BtQ,
    const bf16_t* __restrict__ BtK, const bf16_t* __restrict__ BtV,
    bf16_t* __restrict__ CQ, bf16_t* __restrict__ CK, bf16_t* __restrict__ CV)
{
    __shared__ bf16_t As[128 * 64];
    __shared__ bf16_t Bs[128 * 64];
    const int x = blockIdx.x;
    const bf16_t* Bt; bf16_t* C; int N, col0;
    if (x < 16)      { Bt = BtQ; C = CQ; N = 2048; col0 = x * 128; }
    else if (x < 20) { Bt = BtK; C = CK; N = 512;  col0 = (x - 16) * 128; }
    else             { Bt = BtV; C = CV; N = 512;  col0 = (x - 20) * 128; }
    gemm_bt_body<bf16_t>(A, Bt, C, blockIdx.y * 128, col0, N, 2048, As, Bs);
}

// ---------------------------------------------------------------------------
// Fused prep: x->bf16 conversion + Wq/Wk/Wv fp32->bf16 transposes.
// grid: [0,8192) conv, [8192,12288) Wq, [12288,13312) Wk, [13312,14336) Wv
// ---------------------------------------------------------------------------
__device__ __forceinline__ void transpose_body(
    const float* __restrict__ W, bf16_t* __restrict__ Wt, int K, int N,
    int bx, int by, float (*t)[33], int tid)
{
    int tx = tid & 31, ty = tid >> 5;
    #pragma unroll
    for (int i = 0; i < 32; i += 8)
        t[ty + i][tx] = W[(size_t)(by + ty + i) * N + bx + tx];
    __syncthreads();
    #pragma unroll
    for (int i = 0; i < 32; i += 8)
        Wt[(size_t)(bx + ty + i) * K + by + tx] = (bf16_t)t[tx][ty + i];
}

__global__ __launch_bounds__(256) void prep_all(
    const float* __restrict__ x, const float* __restrict__ Wq,
    const float* __restrict__ Wk, const float* __restrict__ Wv,
    bf16_t* __restrict__ xb, bf16_t* __restrict__ WqT,
    bf16_t* __restrict__ WkT, bf16_t* __restrict__ WvT)
{
    __shared__ float t[32][33];
    const int blk = blockIdx.x, tid = threadIdx.x;
    if (blk < 8192) {
        int i = blk * 256 + tid;
        float4 f = ((const float4*)x)[i];
        bf16x4 v = {(bf16_t)f.x, (bf16_t)f.y, (bf16_t)f.z, (bf16_t)f.w};
        ((bf16x4*)xb)[i] = v;
    } else if (blk < 12288) {
        int r = blk - 8192;
        transpose_body(Wq, WqT, 2048, 2048, (r & 63) * 32, (r >> 6) * 32, t, tid);
    } else if (blk < 13312) {
        int r = blk - 12288;
        transpose_body(Wk, WkT, 2048, 512, (r & 15) * 32, (r >> 4) * 32, t, tid);
    } else {
        int r = blk - 13312;
        transpose_body(Wv, WvT, 2048, 512, (r & 15) * 32, (r >> 4) * 32, t, tid);
    }
}

// ---------------------------------------------------------------------------
// Fused mid: RoPE(K) + V-transpose + Wo-transpose + RoPE(Q)+scale.
// grid: [0,4096) ropeK, [4096,6144) V^T, [6144,10240) Wo, [10240,26624) ropeQ
// RoPE(Q) also folds SCORE_SCALE (1/8 * log2e) so attention loads Q raw.
// ---------------------------------------------------------------------------
__global__ __launch_bounds__(256) void mid_all(
    bf16_t* __restrict__ Kw, const bf16_t* __restrict__ Vw,
    bf16_t* __restrict__ VtG, const float* __restrict__ Wo,
    bf16_t* __restrict__ WoT, bf16_t* __restrict__ Qw)
{
    __shared__ float tf[32][33];
    __shared__ bf16_t tb[32][34];
    const int blk = blockIdx.x, tid = threadIdx.x;
    if (blk < 4096) {
        int idx = blk * 256 + tid;
        int i   = idx & 31;
        int h   = (idx >> 5) & 7;
        int row = idx >> 8;
        float invf = powf(10000.0f, -(float)i / 32.0f);
        float sv, cv;
        sincosf((float)(row & 2047) * invf, &sv, &cv);
        size_t base = (size_t)row * 512 + (size_t)h * 64 + i;
        float a  = (float)Kw[base];
        float b2 = (float)Kw[base + 32];
        Kw[base]      = (bf16_t)(a * cv - b2 * sv);
        Kw[base + 32] = (bf16_t)(b2 * cv + a * sv);
    } else if (blk < 6144) {
        int r  = blk - 4096;
        int bz = r >> 10, r2 = r & 1023;
        int bx = (r2 & 15) * 32, by = (r2 >> 4) * 32;
        int tx = tid & 31, ty = tid >> 5;
        #pragma unroll
        for (int i = 0; i < 32; i += 8)
            tb[ty + i][tx] = Vw[((size_t)bz * 2048 + by + ty + i) * 512 + bx + tx];
        __syncthreads();
        #pragma unroll
        for (int i = 0; i < 32; i += 8)
            VtG[((size_t)bz * 512 + bx + ty + i) * 2048 + by + tx] = tb[tx][ty + i];
    } else if (blk < 10240) {
        int r = blk - 6144;
        transpose_body(Wo, WoT, 2048, 2048, (r & 63) * 32, (r >> 6) * 32, tf, tid);
    } else {
        int idx = (blk - 10240) * 256 + tid;
        int i   = idx & 31;
        int h   = (idx >> 5) & 31;
        int row = idx >> 10;
        float invf = powf(10000.0f, -(float)i / 32.0f);
        float sv, cv;
        sincosf((float)(row & 2047) * invf, &sv, &cv);
        size_t base = (size_t)row * 2048 + (size_t)h * 64 + i;
        float a  = (float)Qw[base];
        float b2 = (float)Qw[base + 32];
        Qw[base]      = (bf16_t)((a * cv - b2 * sv) * SCORE_SCALE);
        Qw[base + 32] = (bf16_t)((b2 * cv + a * sv) * SCORE_SCALE);
    }
}

// ---------------------------------------------------------------------------
// Causal GQA flash attention, transposed register-P formulation.
//   S^T = K.Q^T (16x16x32); P^T = exp2(S^T) (C-layout == B-layout of K=16 mfma)
//   O^T = V^T.P^T (16x16x16, P from registers)
// 64 q-rows/block (wave owns 16) -> grid 1024 = 4 blocks/CU co-resident
// (this round's change: latency-bound loop needs co-residency, m114).
// Q pre-rope'd/pre-scaled. Block pairs q-tiles (31-x, x): 33 iters each.
// K/V double-buffered: global_load_lds + raw s_barrier + vmcnt(4).
// ---------------------------------------------------------------------------
__global__ __launch_bounds__(256) void gqa_attn(
    const bf16_t* __restrict__ Q, const bf16_t* __restrict__ Kc,
    const bf16_t* __restrict__ Vt, bf16_t* __restrict__ AO)
{
    __shared__ alignas(16) bf16_t Ks[2][64 * 64];   // [buf][key][d] swizzled
    __shared__ alignas(16) bf16_t Vs[2][64 * 64];   // [buf][d][key] swizzled (V^T)

    const int x = blockIdx.x, h = blockIdx.y, b = blockIdx.z, g = h >> 2;
    const int tid  = threadIdx.x;
    const int wave = tid >> 6, lane = tid & 63;
    const int quad = lane >> 4, l16 = lane & 15;

    #pragma unroll 1
    for (int t = 0; t < 2; ++t) {
        const int qt = t ? x : (31 - x);
        const int qb = qt * 64 + wave * 16;     // wave's q-row base

        // Q as B-frag (rope'd + scaled): lane holds Q[qb+l16][kh*32+quad*8+j]
        const bf16_t* qp = Q + (size_t)(b * 2048 + qb + l16) * 2048 + h * 64 + quad * 8;
        bf16x8 qf0 = *(const bf16x8*)qp;
        bf16x8 qf1 = *(const bf16x8*)(qp + 32);

        floatx4 o[4] = {};        // O^T: rows d = dt*16+quad*4+r, col q = l16
        floatx4 ls4 = {};         // lsum partials for q-row qb+l16 (4 chains)

        const int ktmax = qt;

        // prefetch kt=0 (prev tile's LDS reads drained at its loop-end barrier)
        #pragma unroll
        for (int i = 0; i < 2; ++i) {
            int c = i * 256 + tid;
            int r = c >> 3, s = c & 7;
            int sw = (s ^ (r & 7)) << 3;
            gld16(Kc + (size_t)(b * 2048 + r) * 512 + g * 64 + sw,
                  &Ks[0][(i * 256 + wave * 64) * 8]);
            gld16(Vt + (size_t)(b * 512 + g * 64 + r) * 2048 + sw,
                  &Vs[0][(i * 256 + wave * 64) * 8]);
        }

        #pragma unroll 1
        for (int kt = 0; kt <= ktmax; ++kt) {
            const int cur = kt & 1;
            if (kt < ktmax) {
                const int kn = kt + 1;
                #pragma unroll
                for (int i = 0; i < 2; ++i) {
                    int c = i * 256 + tid;
                    int r = c >> 3, s = c & 7;
                    int sw = (s ^ (r & 7)) << 3;
                    gld16(Kc + (size_t)(b * 2048 + kn * 64 + r) * 512 + g * 64 + sw,
                          &Ks[cur ^ 1][(i * 256 + wave * 64) * 8]);
                    gld16(Vt + (size_t)(b * 512 + g * 64 + r) * 2048 + kn * 64 + sw,
                          &Vs[cur ^ 1][(i * 256 + wave * 64) * 8]);
                }
                __asm__ volatile("s_waitcnt vmcnt(4)" ::: "memory");
            } else {
                __asm__ volatile("s_waitcnt vmcnt(0)" ::: "memory");
            }
            __builtin_amdgcn_s_barrier();   // buf[cur] fully landed

            // S^T = K.Q^T  (A = K-frag from LDS, B = Q-frag from regs)
            floatx4 st[4] = {};
            #pragma unroll
            for (int nt = 0; nt < 4; ++nt) {
                int kr = nt * 16 + l16;
                bf16x8 kf0 = *(const bf16x8*)&Ks[cur][kr * 64 + ((quad ^ (kr & 7)) << 3)];
                bf16x8 kf1 = *(const bf16x8*)&Ks[cur][kr * 64 + (((4 + quad) ^ (kr & 7)) << 3)];
                st[nt] = MFMA16(kf0, qf0, st[nt]);
                st[nt] = MFMA16(kf1, qf1, st[nt]);
            }

            // diag tile: chunks nt > wave fully masked (skip), nt == wave partial
            const bool diag = (kt == qt);
            const int ntlim = diag ? wave : 3;

            PU pk[4];
            #pragma unroll
            for (int nt = 0; nt < 4; ++nt) {
                if (nt <= ntlim) {
                    float pv[4];
                    #pragma unroll
                    for (int r = 0; r < 4; ++r) {
                        float e = PEXP(st[nt][r]);
                        if (diag && nt == wave) {
                            if (quad * 4 + r > l16) e = 0.f;   // key > q within chunk
                        }
                        ls4[r] += e;
                        pv[r] = e;
                    }
                    pk[nt].v = bf16x4{(bf16_t)pv[0], (bf16_t)pv[1],
                                      (bf16_t)pv[2], (bf16_t)pv[3]};
                } else {
                    pk[nt].u[0] = 0; pk[nt].u[1] = 0;
                }
            }

#ifdef HAVE_MFMA_K16
            // O^T += V^T.P^T  — P^T straight from registers (C==B layout, K=16)
            #pragma unroll
            for (int nt = 0; nt < 4; ++nt) {
                if (nt > ntlim) continue;
                #pragma unroll
                for (int dt = 0; dt < 4; ++dt) {
                    int vr = dt * 16 + l16;
                    int slot = ((nt << 1) | (quad >> 1)) ^ (vr & 7);
                    bf16x4 va = *(const bf16x4*)&Vs[cur][vr * 64 + (slot << 3)
                                                         + ((quad & 1) << 2)];
                    o[dt] = mfma_k16(va, pk[nt].v, o[dt]);
                }
            }
#else
            // Fallback: build K=32 B-frags from pk via cross-lane shfl
            #pragma unroll
            for (int H = 0; H < 2; ++H) {
                BU bfv;
                #pragma unroll
                for (int j = 0; j < 4; ++j) {
                    int srcl = (((quad & 1) << 1) + (j >> 1)) * 16 + l16;
                    unsigned a0 = (unsigned)__shfl((int)pk[2 * H].u[j & 1], srcl, 64);
                    unsigned a1 = (unsigned)__shfl((int)pk[2 * H + 1].u[j & 1], srcl, 64);
                    bfv.u[j] = (quad >> 1) ? a1 : a0;
                }
                #pragma unroll
                for (int dt = 0; dt < 4; ++dt) {
                    int vr = dt * 16 + l16;
                    bf16x8 va = *(const bf16x8*)&Vs[cur][vr * 64
                                  + ((((H << 2) | quad) ^ (vr & 7)) << 3)];
                    o[dt] = MFMA16(va, bfv.v, o[dt]);
                }
            }
#endif
            // reads of buf[cur] retired before next iter's prefetch overwrites
            __asm__ volatile("s_waitcnt lgkmcnt(0)" ::: "memory");
            __builtin_amdgcn_s_barrier();
        }

        // epilogue: finish lsum (4 chains + quad reduce), divide, store O^T
        float l = ls4[0] + ls4[1] + ls4[2] + ls4[3];
        l += __shfl_xor(l, 16, 64);
        l += __shfl_xor(l, 32, 64);
        float rc = 1.0f / l;
        #pragma unroll
        for (int dt = 0; dt < 4; ++dt) {
            bf16x4 ov = {(bf16_t)(o[dt][0] * rc), (bf16_t)(o[dt][1] * rc),
                         (bf16_t)(o[dt][2] * rc), (bf16_t)(o[dt][3] * rc)};
            *(bf16x4*)&AO[(size_t)(b * 2048 + qb + l16) * 2048
                          + h * 64 + dt * 16 + quad * 4] = ov;
        }
    }
}

// ---------------------------------------------------------------------------
extern "C" void kernel_launch(void* const* d_in, const int* in_sizes, int n_in,
                              void* d_out, int out_size, void* d_ws, size_t ws_size,
                              hipStream_t stream)
{
    const float* x  = (const float*)d_in[0];
    const float* Wq = (const float*)d_in[1];
    const float* Wk = (const float*)d_in[2];
    const float* Wv = (const float*)d_in[3];
    const float* Wo = (const float*)d_in[4];
    float* out = (float*)d_out;

    const size_t MB = 1024 * 1024;
    char* ws = (char*)d_ws;
    bf16_t* xb_AO = (bf16_t*)(ws);              // 16 MiB: xb, later AO
    bf16_t* WqoT  = (bf16_t*)(ws + 16 * MB);    //  8 MiB: Wq^T, later Wo^T
    bf16_t* WkT   = (bf16_t*)(ws + 24 * MB);    //  2 MiB
    bf16_t* WvT   = (bf16_t*)(ws + 26 * MB);    //  2 MiB
    bf16_t* Qw    = (bf16_t*)(ws + 28 * MB);    // 16 MiB
    bf16_t* Kw    = (bf16_t*)(ws + 44 * MB);    //  4 MiB
    bf16_t* Vw    = (bf16_t*)(ws + 48 * MB);    //  4 MiB
    bf16_t* VtG   = (bf16_t*)(ws + 52 * MB);    //  4 MiB

    // 1) prep: x->bf16, Wq/Wk/Wv -> transposed bf16
    prep_all<<<14336, 256, 0, stream>>>(x, Wq, Wk, Wv, xb_AO, WqoT, WkT, WvT);

    // 2) fused QKV projection
    gemm_qkv<<<dim3(24, 32), 256, 0, stream>>>(xb_AO, WqoT, WkT, WvT, Qw, Kw, Vw);

    // 3) RoPE(K) + V->V^T + Wo^T + RoPE(Q)+scale
    mid_all<<<26624, 256, 0, stream>>>(Kw, Vw, VtG, Wo, WqoT, Qw);

    // 4) attention (writes AO over dead xb); 1024 blocks = 4/CU
    gqa_attn<<<dim3(16, 32, 2), 256, 0, stream>>>(Qw, Kw, VtG, xb_AO);

    // 5) output projection (fp32 out)
    gemm_bt<float><<<dim3(16, 32), 256, 0, stream>>>(xb_AO, WqoT, out, 2048, 2048);
}